// Round 7
// baseline (3192.771 us; speedup 1.0000x reference)
//
#include <hip/hip_runtime.h>

#define LEAKY 0.2f

// ---------- helpers ----------
__device__ __forceinline__ float h2f(unsigned short b) {
    union { unsigned short u; _Float16 h; } c; c.u = b; return (float)c.h;
}
__device__ __forceinline__ unsigned short f2h(float f) {
    union { unsigned short u; _Float16 h; } c; c.h = (_Float16)f; return c.u;
}
__device__ __forceinline__ void h4(uint2 w, float& a, float& b, float& c, float& d) {
    a = h2f((unsigned short)(w.x & 0xFFFF)); b = h2f((unsigned short)(w.x >> 16));
    c = h2f((unsigned short)(w.y & 0xFFFF)); d = h2f((unsigned short)(w.y >> 16));
}
// float atomic max; segmax initialized to -inf bits. Safe for mixed signs.
__device__ __forceinline__ void atomicMaxF(float* addr, float v) {
    if (v >= 0.f) atomicMax((int*)addr, __float_as_int(v));
    else          atomicMin((unsigned int*)addr, __float_as_uint(v));
}
__device__ __forceinline__ int clampi(int v, int hi) { return v < 0 ? 0 : (v > hi ? hi : v); }
__device__ __forceinline__ int ld_idx(const int* __restrict__ ei, int is64, size_t pos) {
    return is64 ? ei[pos * 2] : ei[pos];
}

// ---- detect int64 vs int32 edge_index (odd 32-bit words all zero => int64) ----
__global__ __launch_bounds__(256) void detect_kernel(const int* __restrict__ ei, int* flag) {
    __shared__ int nz;
    if (threadIdx.x == 0) nz = 0;
    __syncthreads();
    if (ei[2 * threadIdx.x + 1] != 0) atomicOr(&nz, 1);
    __syncthreads();
    if (threadIdx.x == 0) *flag = (nz == 0) ? 1 : 0;
}

// ---- init: zero seg_sum, set seg_max = -inf ----
__global__ __launch_bounds__(256) void init_kernel(float* __restrict__ segsum,
                                                   unsigned* __restrict__ segmax, int nseg) {
    int t = blockIdx.x * 256 + threadIdx.x;
    if (t < nseg) { segsum[t] = 0.f; segmax[t] = 0xFF800000u; }
}

// ---- zero the out_sum accumulator region (d_out lo; hs dead by then) ----
__global__ __launch_bounds__(256) void zero_acc_kernel(float4* __restrict__ acc, int n4) {
    int t = blockIdx.x * 256 + threadIdx.x;
    if (t < n4) acc[t] = make_float4(0.f, 0.f, 0.f, 0.f);
}

// ---- 3 GEMMs: x[N,128] f32 @ W[128,128] f32 -> hs f32, hd f32, hv fp16 ----
// 256 thr: 32 rows x 128 cols/block, 4x4 microtile. LDS 80 KB.
__global__ __launch_bounds__(256) void gemm3_kernel(
    const float* __restrict__ x,
    const float* __restrict__ W0, const float* __restrict__ W1, const float* __restrict__ W2,
    float* __restrict__ o0, float* __restrict__ o1, unsigned short* __restrict__ o2, int N)
{
    __shared__ float Ws[128 * 128];  // 64 KB
    __shared__ float Xs[32 * 128];   // 16 KB
    const int t = threadIdx.x;
    const int row0 = blockIdx.x * 32;

    #pragma unroll
    for (int it = 0; it < 4; ++it) {
        int idx = t + it * 256;          // 0..1023 float4s of X tile
        int r = idx >> 5, c = (idx & 31) * 4;
        float4 v = (row0 + r < N) ? *(const float4*)&x[(size_t)(row0 + r) * 128 + c]
                                  : make_float4(0.f, 0.f, 0.f, 0.f);
        *(float4*)&Xs[r * 128 + c] = v;
    }

    const int rg = t >> 5;   // rows 4*rg..
    const int cg = t & 31;   // cols 4*cg..

    for (int w = 0; w < 3; ++w) {
        const float* Wp = (w == 0) ? W0 : ((w == 1) ? W1 : W2);
        __syncthreads();
        #pragma unroll
        for (int it = 0; it < 16; ++it) {
            int idx = t + it * 256;
            *(float4*)&Ws[idx * 4] = *(const float4*)&Wp[(size_t)idx * 4];
        }
        __syncthreads();

        float acc[4][4] = {};
        for (int k = 0; k < 128; k += 4) {
            float4 a[4], b[4];
            #pragma unroll
            for (int i = 0; i < 4; i++) a[i] = *(const float4*)&Xs[(4 * rg + i) * 128 + k];
            #pragma unroll
            for (int j = 0; j < 4; j++) b[j] = *(const float4*)&Ws[(k + j) * 128 + 4 * cg];
            #pragma unroll
            for (int i = 0; i < 4; i++) {
                acc[i][0] += a[i].x * b[0].x + a[i].y * b[1].x + a[i].z * b[2].x + a[i].w * b[3].x;
                acc[i][1] += a[i].x * b[0].y + a[i].y * b[1].y + a[i].z * b[2].y + a[i].w * b[3].y;
                acc[i][2] += a[i].x * b[0].z + a[i].y * b[1].z + a[i].z * b[2].z + a[i].w * b[3].z;
                acc[i][3] += a[i].x * b[0].w + a[i].y * b[1].w + a[i].z * b[2].w + a[i].w * b[3].w;
            }
        }
        #pragma unroll
        for (int i = 0; i < 4; i++) {
            int gr = row0 + 4 * rg + i;
            if (gr >= N) continue;
            if (w == 2) {
                unsigned p0 = f2h(acc[i][0]) | ((unsigned)f2h(acc[i][1]) << 16);
                unsigned p1 = f2h(acc[i][2]) | ((unsigned)f2h(acc[i][3]) << 16);
                *(uint2*)&o2[(size_t)gr * 128 + 4 * cg] = make_uint2(p0, p1);
            } else {
                float* o = (w == 0) ? o0 : o1;
                *(float4*)&o[(size_t)gr * 128 + 4 * cg] =
                    make_float4(acc[i][0], acc[i][1], acc[i][2], acc[i][3]);
            }
        }
    }
}

// ---- edge scores: 32 lanes/edge, 4 dims/lane; 8-lane dot per head; atomic seg-max ----
__global__ __launch_bounds__(256) void edge_score_kernel(
    const int* __restrict__ ei, const int* __restrict__ iflag,
    const float* __restrict__ hs, const float* __restrict__ hd,
    const float* __restrict__ av,
    float* __restrict__ scores, float* __restrict__ segmax, int N, int E)
{
    size_t tid = (size_t)blockIdx.x * 256 + threadIdx.x;
    size_t e = tid >> 5;
    if (e >= (size_t)E) return;
    int le = (int)(tid & 31);
    int is64 = *iflag;
    int src = clampi(ld_idx(ei, is64, e), N - 1);
    int dst = clampi(ld_idx(ei, is64, (size_t)E + e), N - 1);
    float4 s4 = *(const float4*)&hs[(size_t)src * 128 + le * 4];
    float4 d4 = *(const float4*)&hd[(size_t)dst * 128 + le * 4];
    float4 a4 = *(const float4*)&av[le * 4];
    float m, s = 0.f;
    m = s4.x + d4.x; m = (m > 0.f) ? m : LEAKY * m; s += m * a4.x;
    m = s4.y + d4.y; m = (m > 0.f) ? m : LEAKY * m; s += m * a4.y;
    m = s4.z + d4.z; m = (m > 0.f) ? m : LEAKY * m; s += m * a4.z;
    m = s4.w + d4.w; m = (m > 0.f) ? m : LEAKY * m; s += m * a4.w;
    s += __shfl_xor(s, 1);
    s += __shfl_xor(s, 2);
    s += __shfl_xor(s, 4);
    if ((le & 7) == 0) {
        int h = le >> 3;
        scores[e * 4 + h] = s;
        atomicMaxF(&segmax[(size_t)dst * 4 + h], s);
    }
}

// ---- exp(score - segmax) in place and segment sum ----
__global__ __launch_bounds__(256) void exp_sum_kernel(
    const int* __restrict__ ei, const int* __restrict__ iflag,
    float* __restrict__ scores,
    const float* __restrict__ segmax, float* __restrict__ segsum, int N, int E)
{
    int t = blockIdx.x * 256 + threadIdx.x;
    if (t >= E * 4) return;
    int e = t >> 2, h = t & 3;
    int is64 = *iflag;
    int dst = clampi(ld_idx(ei, is64, (size_t)E + e), N - 1);
    float ex = __expf(scores[t] - segmax[(size_t)dst * 4 + h]);
    scores[t] = ex;
    unsafeAtomicAdd(&segsum[(size_t)dst * 4 + h], ex);
}

// ---- attn = ex/(sum+1e-9) -> f32 attn_out; acc(out_sum f32) += attn * hv ----
__global__ __launch_bounds__(256) void scatter_kernel(
    const int* __restrict__ ei, const int* __restrict__ iflag,
    const float* __restrict__ scores,
    const float* __restrict__ segsum, const unsigned short* __restrict__ hv,
    float* __restrict__ acc, float* __restrict__ attn_out, int N, int E)
{
    size_t tid = (size_t)blockIdx.x * 256 + threadIdx.x;
    size_t e = tid >> 5;
    if (e >= (size_t)E) return;
    int le = (int)(tid & 31);
    int is64 = *iflag;
    int src = clampi(ld_idx(ei, is64, e), N - 1);
    int dst = clampi(ld_idx(ei, is64, (size_t)E + e), N - 1);
    int h = le >> 3;
    float ex = scores[e * 4 + h];
    float a = ex / (segsum[(size_t)dst * 4 + h] + 1e-9f);
    if ((le & 7) == 0) attn_out[e * 4 + h] = a;
    uint2 vw = *(const uint2*)&hv[(size_t)src * 128 + le * 4];
    float v0, v1, v2, v3;
    h4(vw, v0, v1, v2, v3);
    float* ap = &acc[(size_t)dst * 128 + le * 4];
    unsafeAtomicAdd(ap + 0, a * v0);
    unsafeAtomicAdd(ap + 1, a * v1);
    unsafeAtomicAdd(ap + 2, a * v2);
    unsafeAtomicAdd(ap + 3, a * v3);
}

extern "C" void kernel_launch(void* const* d_in, const int* in_sizes, int n_in,
                              void* d_out, int out_size, void* d_ws, size_t ws_size,
                              hipStream_t stream)
{
    const float* x  = (const float*)d_in[0];
    const int* ei   = (const int*)d_in[1];
    const float* W0 = (const float*)d_in[2];
    const float* W1 = (const float*)d_in[3];
    const float* W2 = (const float*)d_in[4];
    const float* av = (const float*)d_in[5];
    const int N = in_sizes[0] / 128;
    const int E = in_sizes[1] / 2;

    // d_out is FP32, out_size = N*128 + E*4 floats (51.2 MB):
    //   [0 .. N*128)          : phase1 hs f32 scratch -> zeroed -> out_sum accumulator (final)
    //   [N*128 .. N*128+E*4)  : phase1 hd f32 scratch -> attn f32 (final; hd dead by scatter)
    float* out_f = (float*)d_out;
    float* hs  = out_f;                      // scratch, dead after edge_score
    float* hd  = out_f + (size_t)N * 128;    // scratch, dead after edge_score
    float* acc = out_f;                      // out_sum accumulated in place
    float* attn_out = out_f + (size_t)N * 128;

    // ws (~40.1 MB): hv fp16 [N*128] | scores f32 [E*4] | segmax [N*4] | segsum [N*4] | iflag
    unsigned short* hv = (unsigned short*)d_ws;
    float* scores = (float*)(hv + (size_t)N * 128);
    float* segmax = scores + (size_t)E * 4;
    float* segsum = segmax + (size_t)N * 4;
    int* iflag = (int*)(segsum + (size_t)N * 4);

    detect_kernel<<<1, 256, 0, stream>>>(ei, iflag);
    init_kernel<<<(N * 4 + 255) / 256, 256, 0, stream>>>(segsum, (unsigned*)segmax, N * 4);
    gemm3_kernel<<<(N + 31) / 32, 256, 0, stream>>>(x, W0, W1, W2, hs, hd, hv, N);
    edge_score_kernel<<<(int)(((size_t)E * 32 + 255) / 256), 256, 0, stream>>>(
        ei, iflag, hs, hd, av, scores, segmax, N, E);
    exp_sum_kernel<<<(int)(((size_t)E * 4 + 255) / 256), 256, 0, stream>>>(
        ei, iflag, scores, segmax, segsum, N, E);
    zero_acc_kernel<<<(N * 32 + 255) / 256, 256, 0, stream>>>((float4*)acc, N * 32);
    scatter_kernel<<<(int)(((size_t)E * 32 + 255) / 256), 256, 0, stream>>>(
        ei, iflag, scores, segsum, hv, acc, attn_out, N, E);
}

// Round 8
// 993.127 us; speedup vs baseline: 3.2149x; 3.2149x over previous
//
#include <hip/hip_runtime.h>

#define LEAKY 0.2f

// ---------- helpers ----------
__device__ __forceinline__ float h2f(unsigned short b) {
    union { unsigned short u; _Float16 h; } c; c.u = b; return (float)c.h;
}
__device__ __forceinline__ unsigned short f2h(float f) {
    union { unsigned short u; _Float16 h; } c; c.h = (_Float16)f; return c.u;
}
__device__ __forceinline__ void h4(uint2 w, float& a, float& b, float& c, float& d) {
    a = h2f((unsigned short)(w.x & 0xFFFF)); b = h2f((unsigned short)(w.x >> 16));
    c = h2f((unsigned short)(w.y & 0xFFFF)); d = h2f((unsigned short)(w.y >> 16));
}
__device__ __forceinline__ int clampi(int v, int hi) { return v < 0 ? 0 : (v > hi ? hi : v); }
__device__ __forceinline__ int ld_idx(const int* __restrict__ ei, int is64, size_t pos) {
    return is64 ? ei[pos * 2] : ei[pos];
}

// ---- detect int64 vs int32 edge_index (odd 32-bit words all zero => int64) ----
__global__ __launch_bounds__(256) void detect_kernel(const int* __restrict__ ei, int* flag) {
    __shared__ int nz;
    if (threadIdx.x == 0) nz = 0;
    __syncthreads();
    if (ei[2 * threadIdx.x + 1] != 0) atomicOr(&nz, 1);
    __syncthreads();
    if (threadIdx.x == 0) *flag = (nz == 0) ? 1 : 0;
}

// ---- init: zero degree histogram and CSR fill cursors ----
__global__ __launch_bounds__(256) void init_kernel(int* __restrict__ deg,
                                                   int* __restrict__ cursor, int N) {
    int t = blockIdx.x * 256 + threadIdx.x;
    if (t < N) { deg[t] = 0; cursor[t] = 0; }
}

// ---- 3 GEMMs: x[N,128] f32 @ W[128,128] f32 -> hs f32, hd f32, hv fp16 ----
__global__ __launch_bounds__(256) void gemm3_kernel(
    const float* __restrict__ x,
    const float* __restrict__ W0, const float* __restrict__ W1, const float* __restrict__ W2,
    float* __restrict__ o0, float* __restrict__ o1, unsigned short* __restrict__ o2, int N)
{
    __shared__ float Ws[128 * 128];  // 64 KB
    __shared__ float Xs[32 * 128];   // 16 KB
    const int t = threadIdx.x;
    const int row0 = blockIdx.x * 32;

    #pragma unroll
    for (int it = 0; it < 4; ++it) {
        int idx = t + it * 256;
        int r = idx >> 5, c = (idx & 31) * 4;
        float4 v = (row0 + r < N) ? *(const float4*)&x[(size_t)(row0 + r) * 128 + c]
                                  : make_float4(0.f, 0.f, 0.f, 0.f);
        *(float4*)&Xs[r * 128 + c] = v;
    }

    const int rg = t >> 5;
    const int cg = t & 31;

    for (int w = 0; w < 3; ++w) {
        const float* Wp = (w == 0) ? W0 : ((w == 1) ? W1 : W2);
        __syncthreads();
        #pragma unroll
        for (int it = 0; it < 16; ++it) {
            int idx = t + it * 256;
            *(float4*)&Ws[idx * 4] = *(const float4*)&Wp[(size_t)idx * 4];
        }
        __syncthreads();

        float acc[4][4] = {};
        for (int k = 0; k < 128; k += 4) {
            float4 a[4], b[4];
            #pragma unroll
            for (int i = 0; i < 4; i++) a[i] = *(const float4*)&Xs[(4 * rg + i) * 128 + k];
            #pragma unroll
            for (int j = 0; j < 4; j++) b[j] = *(const float4*)&Ws[(k + j) * 128 + 4 * cg];
            #pragma unroll
            for (int i = 0; i < 4; i++) {
                acc[i][0] += a[i].x * b[0].x + a[i].y * b[1].x + a[i].z * b[2].x + a[i].w * b[3].x;
                acc[i][1] += a[i].x * b[0].y + a[i].y * b[1].y + a[i].z * b[2].y + a[i].w * b[3].y;
                acc[i][2] += a[i].x * b[0].z + a[i].y * b[1].z + a[i].z * b[2].z + a[i].w * b[3].z;
                acc[i][3] += a[i].x * b[0].w + a[i].y * b[1].w + a[i].z * b[2].w + a[i].w * b[3].w;
            }
        }
        #pragma unroll
        for (int i = 0; i < 4; i++) {
            int gr = row0 + 4 * rg + i;
            if (gr >= N) continue;
            if (w == 2) {
                unsigned p0 = f2h(acc[i][0]) | ((unsigned)f2h(acc[i][1]) << 16);
                unsigned p1 = f2h(acc[i][2]) | ((unsigned)f2h(acc[i][3]) << 16);
                *(uint2*)&o2[(size_t)gr * 128 + 4 * cg] = make_uint2(p0, p1);
            } else {
                float* o = (w == 0) ? o0 : o1;
                *(float4*)&o[(size_t)gr * 128 + 4 * cg] =
                    make_float4(acc[i][0], acc[i][1], acc[i][2], acc[i][3]);
            }
        }
    }
}

// ---- edge scores (raw, no atomics): 32 lanes/edge, 8-lane dot per head ----
__global__ __launch_bounds__(256) void edge_score_kernel(
    const int* __restrict__ ei, const int* __restrict__ iflag,
    const float* __restrict__ hs, const float* __restrict__ hd,
    const float* __restrict__ av, float* __restrict__ scores, int N, int E)
{
    size_t tid = (size_t)blockIdx.x * 256 + threadIdx.x;
    size_t e = tid >> 5;
    if (e >= (size_t)E) return;
    int le = (int)(tid & 31);
    int is64 = *iflag;
    int src = clampi(ld_idx(ei, is64, e), N - 1);
    int dst = clampi(ld_idx(ei, is64, (size_t)E + e), N - 1);
    float4 s4 = *(const float4*)&hs[(size_t)src * 128 + le * 4];
    float4 d4 = *(const float4*)&hd[(size_t)dst * 128 + le * 4];
    float4 a4 = *(const float4*)&av[le * 4];
    float m, s = 0.f;
    m = s4.x + d4.x; m = (m > 0.f) ? m : LEAKY * m; s += m * a4.x;
    m = s4.y + d4.y; m = (m > 0.f) ? m : LEAKY * m; s += m * a4.y;
    m = s4.z + d4.z; m = (m > 0.f) ? m : LEAKY * m; s += m * a4.z;
    m = s4.w + d4.w; m = (m > 0.f) ? m : LEAKY * m; s += m * a4.w;
    s += __shfl_xor(s, 1);
    s += __shfl_xor(s, 2);
    s += __shfl_xor(s, 4);
    if ((le & 7) == 0) scores[e * 4 + (le >> 3)] = s;
}

// ---- CSR build: histogram of dst ----
__global__ __launch_bounds__(256) void hist_kernel(
    const int* __restrict__ ei, const int* __restrict__ iflag,
    int* __restrict__ deg, int N, int E)
{
    int t = blockIdx.x * 256 + threadIdx.x;
    if (t >= E) return;
    int dst = clampi(ld_idx(ei, *iflag, (size_t)E + t), N - 1);
    atomicAdd(&deg[dst], 1);
}

// ---- exclusive scan deg -> offs (single workgroup, chunked Hillis-Steele) ----
__global__ __launch_bounds__(256) void scan_kernel(
    const int* __restrict__ deg, int* __restrict__ offs, int N)
{
    __shared__ int buf[256];
    __shared__ int base;
    if (threadIdx.x == 0) { base = 0; offs[0] = 0; }
    __syncthreads();
    for (int start = 0; start < N; start += 256) {
        int i = start + threadIdx.x;
        int v = (i < N) ? deg[i] : 0;
        buf[threadIdx.x] = v;
        __syncthreads();
        #pragma unroll
        for (int off = 1; off < 256; off <<= 1) {
            int tv = (threadIdx.x >= off) ? buf[threadIdx.x - off] : 0;
            __syncthreads();
            buf[threadIdx.x] += tv;
            __syncthreads();
        }
        if (i < N) offs[i + 1] = base + buf[threadIdx.x];
        __syncthreads();
        if (threadIdx.x == 0) base += buf[255];
        __syncthreads();
    }
}

// ---- CSR fill: sorted[offs[dst] + cursor[dst]++] = edge id ----
__global__ __launch_bounds__(256) void fill_kernel(
    const int* __restrict__ ei, const int* __restrict__ iflag,
    const int* __restrict__ offs, int* __restrict__ cursor,
    int* __restrict__ sorted, int N, int E)
{
    int t = blockIdx.x * 256 + threadIdx.x;
    if (t >= E) return;
    int dst = clampi(ld_idx(ei, *iflag, (size_t)E + t), N - 1);
    int pos = offs[dst] + atomicAdd(&cursor[dst], 1);
    sorted[pos] = t;
}

// ---- gather-reduce: one 64-lane wave per dst; softmax denom + weighted sum ----
// No atomics, no zero pass: each wave owns its 128-float output row.
__global__ __launch_bounds__(256) void gather_kernel(
    const int* __restrict__ ei, const int* __restrict__ iflag,
    const int* __restrict__ offs, const int* __restrict__ sorted,
    const float* __restrict__ scores, const unsigned short* __restrict__ hv,
    float* __restrict__ out, float* __restrict__ segsum, int N, int E)
{
    int wid = (int)(((size_t)blockIdx.x * 256 + threadIdx.x) >> 6);  // dst node
    if (wid >= N) return;
    int lane = threadIdx.x & 63;
    int sub = lane >> 5;   // half-wave 0/1
    int le = lane & 31;
    int h = le >> 3;
    int is64 = *iflag;
    int beg = offs[wid], end = offs[wid + 1];

    // pass 1: softmax denominator (no shift; |score| << 87 so fp32 exp is safe)
    float sum = 0.f;
    for (int j = beg + sub; j < end; j += 2)
        sum += __expf(scores[(size_t)sorted[j] * 4 + h]);
    sum += __shfl_xor(sum, 32);
    float inv = 1.f / (sum + 1e-9f);

    // pass 2: weighted aggregation of h_v
    float a0 = 0.f, a1 = 0.f, a2 = 0.f, a3 = 0.f;
    for (int j = beg + sub; j < end; j += 2) {
        int eid = sorted[j];
        float a = __expf(scores[(size_t)eid * 4 + h]) * inv;
        int src = clampi(ld_idx(ei, is64, (size_t)eid), N - 1);
        uint2 vw = *(const uint2*)&hv[(size_t)src * 128 + le * 4];
        float v0, v1, v2, v3;
        h4(vw, v0, v1, v2, v3);
        a0 += a * v0; a1 += a * v1; a2 += a * v2; a3 += a * v3;
    }
    a0 += __shfl_xor(a0, 32); a1 += __shfl_xor(a1, 32);
    a2 += __shfl_xor(a2, 32); a3 += __shfl_xor(a3, 32);
    if (sub == 0) {
        *(float4*)&out[(size_t)wid * 128 + le * 4] = make_float4(a0, a1, a2, a3);
        if ((le & 7) == 0) segsum[wid * 4 + h] = sum;
    }
}

// ---- attn output (coalesced, runs last; overwrites sorted scratch) ----
__global__ __launch_bounds__(256) void attn_write_kernel(
    const int* __restrict__ ei, const int* __restrict__ iflag,
    const float* __restrict__ scores, const float* __restrict__ segsum,
    float* __restrict__ attn_out, int N, int E)
{
    int t = blockIdx.x * 256 + threadIdx.x;
    if (t >= E * 4) return;
    int e = t >> 2, h = t & 3;
    int dst = clampi(ld_idx(ei, *iflag, (size_t)E + e), N - 1);
    attn_out[t] = __expf(scores[t]) / (segsum[(size_t)dst * 4 + h] + 1e-9f);
}

extern "C" void kernel_launch(void* const* d_in, const int* in_sizes, int n_in,
                              void* d_out, int out_size, void* d_ws, size_t ws_size,
                              hipStream_t stream)
{
    const float* x  = (const float*)d_in[0];
    const int* ei   = (const int*)d_in[1];
    const float* W0 = (const float*)d_in[2];
    const float* W1 = (const float*)d_in[3];
    const float* W2 = (const float*)d_in[4];
    const float* av = (const float*)d_in[5];
    const int N = in_sizes[0] / 128;
    const int E = in_sizes[1] / 2;

    // d_out fp32 (N*128 + E*4 floats):
    //   lo [0..N*128)        : hs scratch -> out_sum (gather writes directly, no zero)
    //   hi [N*128..+E*4)     : hd scratch -> sorted (E ints) -> attn (final)
    float* out_f = (float*)d_out;
    float* hs  = out_f;
    float* hd  = out_f + (size_t)N * 128;
    float* out_sum = out_f;
    float* attn_out = out_f + (size_t)N * 128;
    int* sorted = (int*)(out_f + (size_t)N * 128);

    // ws (~40 MB): hv fp16 [N*128] | scores f32 [E*4] | segsum f32 [N*4]
    //            | cursor int [N] | deg int [N] | offs int [N+1] | iflag
    unsigned short* hv = (unsigned short*)d_ws;
    float* scores = (float*)(hv + (size_t)N * 128);
    float* segsum = scores + (size_t)E * 4;
    int* cursor = (int*)(segsum + (size_t)N * 4);
    int* deg = cursor + N;
    int* offs = deg + N;
    int* iflag = offs + (N + 1);

    detect_kernel<<<1, 256, 0, stream>>>(ei, iflag);
    init_kernel<<<(N + 255) / 256, 256, 0, stream>>>(deg, cursor, N);
    gemm3_kernel<<<(N + 31) / 32, 256, 0, stream>>>(x, W0, W1, W2, hs, hd, hv, N);
    edge_score_kernel<<<(int)(((size_t)E * 32 + 255) / 256), 256, 0, stream>>>(
        ei, iflag, hs, hd, av, scores, N, E);
    hist_kernel<<<(E + 255) / 256, 256, 0, stream>>>(ei, iflag, deg, N, E);
    scan_kernel<<<1, 256, 0, stream>>>(deg, offs, N);
    fill_kernel<<<(E + 255) / 256, 256, 0, stream>>>(ei, iflag, offs, cursor, sorted, N, E);
    gather_kernel<<<(N + 3) / 4, 256, 0, stream>>>(
        ei, iflag, offs, sorted, scores, hv, out_sum, segsum, N, E);
    attn_write_kernel<<<(E * 4 + 255) / 256, 256, 0, stream>>>(
        ei, iflag, scores, segsum, attn_out, N, E);
}